// Round 4
// baseline (71.656 us; speedup 1.0000x reference)
//
#include <hip/hip_runtime.h>
#include <math.h>

#define EPSF 1e-5f
constexpr int NT  = 1024;
constexpr int ND  = 128;
constexpr int KIN = 19;
constexpr int H   = 256;
constexpr int L   = 128;
constexpr int T   = 4;      // tiles (b,t) per block, one per wave

typedef __attribute__((ext_vector_type(8))) short short8;
typedef __attribute__((ext_vector_type(4))) float f32x4;

static __device__ inline ushort f2bf(float f) {
    unsigned u = __float_as_uint(f);
    unsigned r = (u + 0x7fffu + ((u >> 16) & 1u)) >> 16;
    return (ushort)r;
}

// Kernel A: features + bf16 MFMA layer0 + leaky + mean-pool -> hm[4096][256]
__global__ __launch_bounds__(256, 4) void k_feat_l0(
    const float* __restrict__ x0, const float* __restrict__ x,
    const int*   __restrict__ Nv, const float* __restrict__ basis,
    const float* __restrict__ v,  const float* __restrict__ W0,
    const float* __restrict__ b0, float* __restrict__ hm_out)
{
    const int tid  = threadIdx.x;
    const int lane = tid & 63;
    const int w    = tid >> 6;               // wave id == local t
    const int g    = blockIdx.x * T + w;     // this wave's (b,t)
    const int bidx = g >> 10;

    // A-fragments: [t][mt*64 + kb*16 + r16] of short8  (32 KB)
    __shared__ __align__(16) ushort featb[T * 512 * 8];

    // ---- B fragments (W0 bf16, cols [w*64, w*64+64)) + bias C-in ----
    short8 bfrag[4];
    f32x4  cb[4];
    {
        const int col16 = lane & 15;
        const int kb    = lane >> 4;
        #pragma unroll
        for (int nt = 0; nt < 4; ++nt) {
            const int col = w * 64 + nt * 16 + col16;
            short8 bv;
            #pragma unroll
            for (int j = 0; j < 8; ++j) {
                const int k = kb * 8 + j;
                float val = (k < KIN) ? W0[k * H + col] : 0.f;
                bv[j] = (short)f2bf(val);
            }
            bfrag[nt] = bv;
            const float bb = b0[col];
            #pragma unroll
            for (int r = 0; r < 4; ++r) cb[nt][r] = bb;
        }
    }

    // ---- per-lane loads: d0 = lane, d1 = lane+64 (coalesced 12B/lane) ----
    const float* xp = x + (size_t)g * (ND * 3);
    const float* vp = v + (size_t)g * (ND * 3);
    float X[2][3], V[2][3];
    #pragma unroll
    for (int i = 0; i < 2; ++i) {
        const int d = lane + i * 64;
        X[i][0] = xp[d*3+0]; X[i][1] = xp[d*3+1]; X[i][2] = xp[d*3+2];
        V[i][0] = vp[d*3+0]; V[i][1] = vp[d*3+1]; V[i][2] = vp[d*3+2];
    }

    // ---- v0 via wave shuffle reduce (no LDS, no barriers) ----
    float sx = V[0][0] + V[1][0];
    float sy = V[0][1] + V[1][1];
    float sz = V[0][2] + V[1][2];
    #pragma unroll
    for (int m = 1; m < 64; m <<= 1) {
        sx += __shfl_xor(sx, m, 64);
        sy += __shfl_xor(sy, m, 64);
        sz += __shfl_xor(sz, m, 64);
    }
    const float invd = 1.0f / (float)ND;
    const float v0x = sx * invd, v0y = sy * invd, v0z = sz * invd;

    // ---- block-uniform scalars (all lanes redundantly) ----
    float fs[10];
    {
        const float ax = x0[g*3+0], ay = x0[g*3+1], az = x0[g*3+2];
        const float x0n = sqrtf(ax*ax + ay*ay + az*az) + EPSF;
        const float v0n = sqrtf(v0x*v0x + v0y*v0y + v0z*v0z) + EPSF;
        const float ix  = 1.f / x0n, iv0 = 1.f / v0n;
        const float* bs = basis + bidx * 9;
        fs[0] = log1pf((float)Nv[g]);
        fs[1] = x0n;
        fs[2] = (ax*bs[0] + ay*bs[1] + az*bs[2]) * ix;
        fs[3] = (ax*bs[3] + ay*bs[4] + az*bs[5]) * ix;
        fs[4] = (ax*bs[6] + ay*bs[7] + az*bs[8]) * ix;
        fs[5] = v0n;
        fs[6] = (v0x*bs[0] + v0y*bs[1] + v0z*bs[2]) * iv0;
        fs[7] = (v0x*bs[3] + v0y*bs[4] + v0z*bs[5]) * iv0;
        fs[8] = (v0x*bs[6] + v0y*bs[7] + v0z*bs[8]) * iv0;
        fs[9] = (ax*v0x + ay*v0y + az*v0z) * ix * iv0;
    }

    // ---- per-d features -> bf16 A-fragments in LDS ----
    const float* bs = basis + bidx * 9;
    #pragma unroll
    for (int i = 0; i < 2; ++i) {
        const int d  = lane + i * 64;
        const float cx = V[i][0] - v0x, cy = V[i][1] - v0y, cz = V[i][2] - v0z;
        const float xx = X[i][0], xy = X[i][1], xz = X[i][2];
        const float xn = sqrtf(xx*xx + xy*xy + xz*xz) + EPSF;
        const float vn = sqrtf(cx*cx + cy*cy + cz*cz) + EPSF;
        const float ixn = 1.f/xn, ivn = 1.f/vn;
        float f[32];
        #pragma unroll
        for (int k = 0; k < 10; ++k) f[k] = fs[k];
        f[10] = xn;
        f[11] = (xx*bs[0] + xy*bs[1] + xz*bs[2]) * ixn;
        f[12] = (xx*bs[3] + xy*bs[4] + xz*bs[5]) * ixn;
        f[13] = (xx*bs[6] + xy*bs[7] + xz*bs[8]) * ixn;
        f[14] = vn;
        f[15] = (cx*bs[0] + cy*bs[1] + cz*bs[2]) * ivn;
        f[16] = (cx*bs[3] + cy*bs[4] + cz*bs[5]) * ivn;
        f[17] = (cx*bs[6] + cy*bs[7] + cz*bs[8]) * ivn;
        f[18] = (xx*cx + xy*cy + xz*cz) * ixn * ivn;
        #pragma unroll
        for (int k = KIN; k < 32; ++k) f[k] = 0.f;
        const int mt  = d >> 4;
        const int r16 = d & 15;
        #pragma unroll
        for (int kb2 = 0; kb2 < 4; ++kb2) {
            short8 c;
            #pragma unroll
            for (int j = 0; j < 8; ++j) c[j] = (short)f2bf(f[kb2*8 + j]);
            *reinterpret_cast<short8*>(&featb[((w << 9) + (mt << 6) + (kb2 << 4) + r16) * 8]) = c;
        }
    }
    __syncthreads();   // the only barrier

    // ---- MFMA phase: per wave, loop t; psum live only within one t ----
    #pragma unroll 1
    for (int t = 0; t < T; ++t) {
        f32x4 psum[4];
        #pragma unroll
        for (int nt = 0; nt < 4; ++nt)
            #pragma unroll
            for (int r = 0; r < 4; ++r) psum[nt][r] = 0.f;

        #pragma unroll
        for (int mt = 0; mt < 8; ++mt) {
            const short8 af = *reinterpret_cast<const short8*>(
                &featb[((t << 9) + (mt << 6) + lane) * 8]);
            #pragma unroll
            for (int nt = 0; nt < 4; ++nt) {
                f32x4 d = __builtin_amdgcn_mfma_f32_16x16x32_bf16(af, bfrag[nt], cb[nt], 0, 0, 0);
                #pragma unroll
                for (int r = 0; r < 4; ++r) {
                    const float a = d[r];
                    psum[nt][r] += fmaxf(a, 0.01f * a);
                }
            }
        }

        // epilogue for this t: column pool across lane groups, write hm
        const int gg = blockIdx.x * T + t;
        #pragma unroll
        for (int nt = 0; nt < 4; ++nt) {
            float s4 = psum[nt][0] + psum[nt][1] + psum[nt][2] + psum[nt][3];
            s4 += __shfl_xor(s4, 16, 64);
            s4 += __shfl_xor(s4, 32, 64);
            if (lane < 16)
                hm_out[(size_t)gg * H + w * 64 + nt * 16 + lane] = s4 * invd;
        }
    }
}

// Kernel B: layers 1-2, 8 t per block (unchanged)
__global__ __launch_bounds__(256) void k_l12(
    const float* __restrict__ hm, const float* __restrict__ W1,
    const float* __restrict__ b1, const float* __restrict__ W2,
    const float* __restrict__ b2, float* __restrict__ out)
{
    const int tb  = blockIdx.x * 8;
    const int tid = threadIdx.x;
    __shared__ float hs[8][H];
    __shared__ float h1[8][H];

    {
        const float4* src = reinterpret_cast<const float4*>(hm + (size_t)tb * H);
        float4* dst = reinterpret_cast<float4*>(&hs[0][0]);
        #pragma unroll
        for (int i = 0; i < 2; ++i) dst[tid + i*256] = src[tid + i*256];
    }
    __syncthreads();

    {
        float acc[8];
        const float bb = b1[tid];
        #pragma unroll
        for (int t = 0; t < 8; ++t) acc[t] = bb;
        for (int k = 0; k < H; ++k) {
            const float w = W1[(size_t)k * H + tid];
            #pragma unroll
            for (int t = 0; t < 8; ++t) acc[t] = fmaf(hs[t][k], w, acc[t]);
        }
        #pragma unroll
        for (int t = 0; t < 8; ++t) {
            float a = acc[t];
            h1[t][tid] = (a > 0.f) ? a : 0.01f * a;
        }
    }
    __syncthreads();

    {
        const int n  = tid & 127;
        const int t0 = (tid >> 7) * 4;
        float acc[4];
        const float bb = b2[n];
        #pragma unroll
        for (int t = 0; t < 4; ++t) acc[t] = bb;
        for (int k = 0; k < H; ++k) {
            const float w = W2[(size_t)k * L + n];
            #pragma unroll
            for (int t = 0; t < 4; ++t) acc[t] = fmaf(h1[t0 + t][k], w, acc[t]);
        }
        #pragma unroll
        for (int t = 0; t < 4; ++t)
            out[(size_t)(tb + t0 + t) * L + n] = acc[t];
    }
}

extern "C" void kernel_launch(void* const* d_in, const int* in_sizes, int n_in,
                              void* d_out, int out_size, void* d_ws, size_t ws_size,
                              hipStream_t stream) {
    const float* x0    = (const float*)d_in[0];
    const float* x     = (const float*)d_in[1];
    const int*   Nv    = (const int*)  d_in[2];
    const float* basis = (const float*)d_in[3];
    const float* v     = (const float*)d_in[4];
    const float* W0    = (const float*)d_in[5];
    const float* b0    = (const float*)d_in[6];
    const float* W1    = (const float*)d_in[7];
    const float* b1    = (const float*)d_in[8];
    const float* W2    = (const float*)d_in[9];
    const float* b2    = (const float*)d_in[10];
    float* out = (float*)d_out;
    float* hm  = (float*)d_ws;          // 4096*256*4 = 4 MB

    hipLaunchKernelGGL(k_feat_l0, dim3(4 * NT / T), dim3(256), 0, stream,
                       x0, x, Nv, basis, v, W0, b0, hm);
    hipLaunchKernelGGL(k_l12, dim3(4 * NT / 8), dim3(256), 0, stream,
                       hm, W1, b1, W2, b2, out);
}

// Round 5
// 54.420 us; speedup vs baseline: 1.3167x; 1.3167x over previous
//
#include <hip/hip_runtime.h>
#include <math.h>

#define EPSF 1e-5f
constexpr int NT  = 1024;
constexpr int ND  = 128;
constexpr int KIN = 19;
constexpr int H   = 256;
constexpr int L   = 128;
constexpr int T   = 4;      // tiles (b,t) per block, one per wave

typedef __attribute__((ext_vector_type(8))) short short8;
typedef __attribute__((ext_vector_type(4))) float f32x4;

static __device__ inline ushort f2bf(float f) {
    unsigned u = __float_as_uint(f);
    unsigned r = (u + 0x7fffu + ((u >> 16) & 1u)) >> 16;
    return (ushort)r;
}

// Kernel A: features + bf16 MFMA layer0 + leaky + mean-pool -> hm[4096][256]
// NOTE: no min-waves hint — __launch_bounds__(256,4) made the allocator chase
// the 64-VGPR/8-wave bracket and spill ~80B/thread to scratch (R4: 85MB WRITE).
__global__ __launch_bounds__(256) void k_feat_l0(
    const float* __restrict__ x0, const float* __restrict__ x,
    const int*   __restrict__ Nv, const float* __restrict__ basis,
    const float* __restrict__ v,  const float* __restrict__ W0,
    const float* __restrict__ b0, float* __restrict__ hm_out)
{
    const int tid  = threadIdx.x;
    const int lane = tid & 63;
    const int w    = tid >> 6;               // wave id == local t
    const int g    = blockIdx.x * T + w;     // this wave's (b,t)
    const int bidx = g >> 10;

    // A-fragments: [t][mt*64 + kb*16 + r16] of short8  (32 KB)
    __shared__ __align__(16) ushort featb[T * 512 * 8];

    // ---- B fragments (W0 bf16, cols [w*64, w*64+64)) + bias C-in ----
    short8 bfrag[4];
    f32x4  cb[4];
    {
        const int col16 = lane & 15;
        const int kb    = lane >> 4;
        #pragma unroll
        for (int nt = 0; nt < 4; ++nt) {
            const int col = w * 64 + nt * 16 + col16;
            short8 bv;
            #pragma unroll
            for (int j = 0; j < 8; ++j) {
                const int k = kb * 8 + j;
                float val = (k < KIN) ? W0[k * H + col] : 0.f;
                bv[j] = (short)f2bf(val);
            }
            bfrag[nt] = bv;
            const float bb = b0[col];
            #pragma unroll
            for (int r = 0; r < 4; ++r) cb[nt][r] = bb;
        }
    }

    // ---- per-lane loads: d0 = lane, d1 = lane+64 (coalesced 12B/lane) ----
    const float* xp = x + (size_t)g * (ND * 3);
    const float* vp = v + (size_t)g * (ND * 3);
    float X[2][3], V[2][3];
    #pragma unroll
    for (int i = 0; i < 2; ++i) {
        const int d = lane + i * 64;
        X[i][0] = xp[d*3+0]; X[i][1] = xp[d*3+1]; X[i][2] = xp[d*3+2];
        V[i][0] = vp[d*3+0]; V[i][1] = vp[d*3+1]; V[i][2] = vp[d*3+2];
    }

    // ---- v0 via wave shuffle reduce (no LDS, no barriers) ----
    float sx = V[0][0] + V[1][0];
    float sy = V[0][1] + V[1][1];
    float sz = V[0][2] + V[1][2];
    #pragma unroll
    for (int m = 1; m < 64; m <<= 1) {
        sx += __shfl_xor(sx, m, 64);
        sy += __shfl_xor(sy, m, 64);
        sz += __shfl_xor(sz, m, 64);
    }
    const float invd = 1.0f / (float)ND;
    const float v0x = sx * invd, v0y = sy * invd, v0z = sz * invd;

    // ---- block-uniform scalars (all lanes redundantly) ----
    float fs[10];
    {
        const float ax = x0[g*3+0], ay = x0[g*3+1], az = x0[g*3+2];
        const float x0n = sqrtf(ax*ax + ay*ay + az*az) + EPSF;
        const float v0n = sqrtf(v0x*v0x + v0y*v0y + v0z*v0z) + EPSF;
        const float ix  = 1.f / x0n, iv0 = 1.f / v0n;
        const float* bs = basis + bidx * 9;
        fs[0] = log1pf((float)Nv[g]);
        fs[1] = x0n;
        fs[2] = (ax*bs[0] + ay*bs[1] + az*bs[2]) * ix;
        fs[3] = (ax*bs[3] + ay*bs[4] + az*bs[5]) * ix;
        fs[4] = (ax*bs[6] + ay*bs[7] + az*bs[8]) * ix;
        fs[5] = v0n;
        fs[6] = (v0x*bs[0] + v0y*bs[1] + v0z*bs[2]) * iv0;
        fs[7] = (v0x*bs[3] + v0y*bs[4] + v0z*bs[5]) * iv0;
        fs[8] = (v0x*bs[6] + v0y*bs[7] + v0z*bs[8]) * iv0;
        fs[9] = (ax*v0x + ay*v0y + az*v0z) * ix * iv0;
    }

    // ---- per-d features -> bf16 A-fragments in LDS ----
    const float* bs = basis + bidx * 9;
    #pragma unroll
    for (int i = 0; i < 2; ++i) {
        const int d  = lane + i * 64;
        const float cx = V[i][0] - v0x, cy = V[i][1] - v0y, cz = V[i][2] - v0z;
        const float xx = X[i][0], xy = X[i][1], xz = X[i][2];
        const float xn = sqrtf(xx*xx + xy*xy + xz*xz) + EPSF;
        const float vn = sqrtf(cx*cx + cy*cy + cz*cz) + EPSF;
        const float ixn = 1.f/xn, ivn = 1.f/vn;
        float f[32];
        #pragma unroll
        for (int k = 0; k < 10; ++k) f[k] = fs[k];
        f[10] = xn;
        f[11] = (xx*bs[0] + xy*bs[1] + xz*bs[2]) * ixn;
        f[12] = (xx*bs[3] + xy*bs[4] + xz*bs[5]) * ixn;
        f[13] = (xx*bs[6] + xy*bs[7] + xz*bs[8]) * ixn;
        f[14] = vn;
        f[15] = (cx*bs[0] + cy*bs[1] + cz*bs[2]) * ivn;
        f[16] = (cx*bs[3] + cy*bs[4] + cz*bs[5]) * ivn;
        f[17] = (cx*bs[6] + cy*bs[7] + cz*bs[8]) * ivn;
        f[18] = (xx*cx + xy*cy + xz*cz) * ixn * ivn;
        #pragma unroll
        for (int k = KIN; k < 32; ++k) f[k] = 0.f;
        const int mt  = d >> 4;
        const int r16 = d & 15;
        #pragma unroll
        for (int kb2 = 0; kb2 < 4; ++kb2) {
            short8 c;
            #pragma unroll
            for (int j = 0; j < 8; ++j) c[j] = (short)f2bf(f[kb2*8 + j]);
            *reinterpret_cast<short8*>(&featb[((w << 9) + (mt << 6) + (kb2 << 4) + r16) * 8]) = c;
        }
    }
    __syncthreads();   // the only barrier

    // ---- MFMA phase: per wave, loop t; psum live only within one t ----
    #pragma unroll 1
    for (int t = 0; t < T; ++t) {
        f32x4 psum[4];
        #pragma unroll
        for (int nt = 0; nt < 4; ++nt)
            #pragma unroll
            for (int r = 0; r < 4; ++r) psum[nt][r] = 0.f;

        #pragma unroll
        for (int mt = 0; mt < 8; ++mt) {
            const short8 af = *reinterpret_cast<const short8*>(
                &featb[((t << 9) + (mt << 6) + lane) * 8]);
            #pragma unroll
            for (int nt = 0; nt < 4; ++nt) {
                f32x4 d = __builtin_amdgcn_mfma_f32_16x16x32_bf16(af, bfrag[nt], cb[nt], 0, 0, 0);
                #pragma unroll
                for (int r = 0; r < 4; ++r) {
                    const float a = d[r];
                    psum[nt][r] += fmaxf(a, 0.01f * a);
                }
            }
        }

        // epilogue for this t: column pool across lane groups, write hm
        const int gg = blockIdx.x * T + t;
        #pragma unroll
        for (int nt = 0; nt < 4; ++nt) {
            float s4 = psum[nt][0] + psum[nt][1] + psum[nt][2] + psum[nt][3];
            s4 += __shfl_xor(s4, 16, 64);
            s4 += __shfl_xor(s4, 32, 64);
            if (lane < 16)
                hm_out[(size_t)gg * H + w * 64 + nt * 16 + lane] = s4 * invd;
        }
    }
}

// Kernel B: layers 1-2, 8 t per block (unchanged)
__global__ __launch_bounds__(256) void k_l12(
    const float* __restrict__ hm, const float* __restrict__ W1,
    const float* __restrict__ b1, const float* __restrict__ W2,
    const float* __restrict__ b2, float* __restrict__ out)
{
    const int tb  = blockIdx.x * 8;
    const int tid = threadIdx.x;
    __shared__ float hs[8][H];
    __shared__ float h1[8][H];

    {
        const float4* src = reinterpret_cast<const float4*>(hm + (size_t)tb * H);
        float4* dst = reinterpret_cast<float4*>(&hs[0][0]);
        #pragma unroll
        for (int i = 0; i < 2; ++i) dst[tid + i*256] = src[tid + i*256];
    }
    __syncthreads();

    {
        float acc[8];
        const float bb = b1[tid];
        #pragma unroll
        for (int t = 0; t < 8; ++t) acc[t] = bb;
        for (int k = 0; k < H; ++k) {
            const float w = W1[(size_t)k * H + tid];
            #pragma unroll
            for (int t = 0; t < 8; ++t) acc[t] = fmaf(hs[t][k], w, acc[t]);
        }
        #pragma unroll
        for (int t = 0; t < 8; ++t) {
            float a = acc[t];
            h1[t][tid] = (a > 0.f) ? a : 0.01f * a;
        }
    }
    __syncthreads();

    {
        const int n  = tid & 127;
        const int t0 = (tid >> 7) * 4;
        float acc[4];
        const float bb = b2[n];
        #pragma unroll
        for (int t = 0; t < 4; ++t) acc[t] = bb;
        for (int k = 0; k < H; ++k) {
            const float w = W2[(size_t)k * L + n];
            #pragma unroll
            for (int t = 0; t < 4; ++t) acc[t] = fmaf(h1[t0 + t][k], w, acc[t]);
        }
        #pragma unroll
        for (int t = 0; t < 4; ++t)
            out[(size_t)(tb + t0 + t) * L + n] = acc[t];
    }
}

extern "C" void kernel_launch(void* const* d_in, const int* in_sizes, int n_in,
                              void* d_out, int out_size, void* d_ws, size_t ws_size,
                              hipStream_t stream) {
    const float* x0    = (const float*)d_in[0];
    const float* x     = (const float*)d_in[1];
    const int*   Nv    = (const int*)  d_in[2];
    const float* basis = (const float*)d_in[3];
    const float* v     = (const float*)d_in[4];
    const float* W0    = (const float*)d_in[5];
    const float* b0    = (const float*)d_in[6];
    const float* W1    = (const float*)d_in[7];
    const float* b1    = (const float*)d_in[8];
    const float* W2    = (const float*)d_in[9];
    const float* b2    = (const float*)d_in[10];
    float* out = (float*)d_out;
    float* hm  = (float*)d_ws;          // 4096*256*4 = 4 MB

    hipLaunchKernelGGL(k_feat_l0, dim3(4 * NT / T), dim3(256), 0, stream,
                       x0, x, Nv, basis, v, W0, b0, hm);
    hipLaunchKernelGGL(k_l12, dim3(4 * NT / 8), dim3(256), 0, stream,
                       hm, W1, b1, W2, b2, out);
}

// Round 6
// 48.057 us; speedup vs baseline: 1.4910x; 1.1324x over previous
//
#include <hip/hip_runtime.h>
#include <math.h>

#define EPSF 1e-5f
constexpr int NT  = 1024;
constexpr int ND  = 128;
constexpr int KIN = 19;
constexpr int H   = 256;
constexpr int L   = 128;
constexpr int T   = 4;      // tiles (b,t) per block, one per wave

typedef __attribute__((ext_vector_type(8))) short short8;
typedef __attribute__((ext_vector_type(4))) float f32x4;

// packed fp32->bf16 (RNE), 2 elements per instruction
static __device__ inline unsigned cvt_pk_bf16(float lo, float hi) {
    unsigned r;
    asm("v_cvt_pk_bf16_f32 %0, %1, %2" : "=v"(r) : "v"(lo), "v"(hi));
    return r;
}

// Kernel A: features + bf16 MFMA layer0 + leaky + mean-pool -> hm[4096][256]
__global__ __launch_bounds__(256) void k_feat_l0(
    const float* __restrict__ x0, const float* __restrict__ x,
    const int*   __restrict__ Nv, const float* __restrict__ basis,
    const float* __restrict__ v,  const float* __restrict__ W0,
    const float* __restrict__ b0, float* __restrict__ hm_out)
{
    const int tid  = threadIdx.x;
    const int lane = tid & 63;
    const int w    = tid >> 6;               // wave id == local t
    const int g    = blockIdx.x * T + w;     // this wave's (b,t)
    const int bidx = g >> 10;

    // A-fragments: [t][mt*64 + kb*16 + r16] of short8  (32 KB)
    __shared__ __align__(16) ushort featb[T * 512 * 8];

    // ---- B fragments: k<19 = W0 row k; k==19 = b0 (bias-as-feature); k>19 = 0
    short8 bfrag[4];
    {
        const int col16 = lane & 15;
        const int kb    = lane >> 4;
        #pragma unroll
        for (int nt = 0; nt < 4; ++nt) {
            const int col = w * 64 + nt * 16 + col16;
            float fv[8];
            #pragma unroll
            for (int j = 0; j < 8; ++j) {
                const int k = kb * 8 + j;
                fv[j] = (k < KIN) ? W0[k * H + col] : ((k == KIN) ? b0[col] : 0.f);
            }
            uint4 pk;
            pk.x = cvt_pk_bf16(fv[0], fv[1]);
            pk.y = cvt_pk_bf16(fv[2], fv[3]);
            pk.z = cvt_pk_bf16(fv[4], fv[5]);
            pk.w = cvt_pk_bf16(fv[6], fv[7]);
            bfrag[nt] = *reinterpret_cast<short8*>(&pk);
        }
    }

    // ---- per-lane loads: d0 = lane, d1 = lane+64 (coalesced 12B/lane) ----
    const float* xp = x + (size_t)g * (ND * 3);
    const float* vp = v + (size_t)g * (ND * 3);
    float X[2][3], V[2][3];
    #pragma unroll
    for (int i = 0; i < 2; ++i) {
        const int d = lane + i * 64;
        X[i][0] = xp[d*3+0]; X[i][1] = xp[d*3+1]; X[i][2] = xp[d*3+2];
        V[i][0] = vp[d*3+0]; V[i][1] = vp[d*3+1]; V[i][2] = vp[d*3+2];
    }

    // ---- v0 via wave shuffle reduce (no LDS, no barriers) ----
    float sx = V[0][0] + V[1][0];
    float sy = V[0][1] + V[1][1];
    float sz = V[0][2] + V[1][2];
    #pragma unroll
    for (int m = 1; m < 64; m <<= 1) {
        sx += __shfl_xor(sx, m, 64);
        sy += __shfl_xor(sy, m, 64);
        sz += __shfl_xor(sz, m, 64);
    }
    const float invd = 1.0f / (float)ND;
    const float v0x = sx * invd, v0y = sy * invd, v0z = sz * invd;

    // ---- block-uniform scalars (all lanes redundantly) ----
    float fs[10];
    {
        const float ax = x0[g*3+0], ay = x0[g*3+1], az = x0[g*3+2];
        const float x0n = sqrtf(ax*ax + ay*ay + az*az) + EPSF;
        const float v0n = sqrtf(v0x*v0x + v0y*v0y + v0z*v0z) + EPSF;
        const float ix  = 1.f / x0n, iv0 = 1.f / v0n;
        const float* bs = basis + bidx * 9;
        fs[0] = log1pf((float)Nv[g]);
        fs[1] = x0n;
        fs[2] = (ax*bs[0] + ay*bs[1] + az*bs[2]) * ix;
        fs[3] = (ax*bs[3] + ay*bs[4] + az*bs[5]) * ix;
        fs[4] = (ax*bs[6] + ay*bs[7] + az*bs[8]) * ix;
        fs[5] = v0n;
        fs[6] = (v0x*bs[0] + v0y*bs[1] + v0z*bs[2]) * iv0;
        fs[7] = (v0x*bs[3] + v0y*bs[4] + v0z*bs[5]) * iv0;
        fs[8] = (v0x*bs[6] + v0y*bs[7] + v0z*bs[8]) * iv0;
        fs[9] = (ax*v0x + ay*v0y + az*v0z) * ix * iv0;
    }

    // ---- per-d features -> bf16 A-fragments in LDS (cvt_pk packing) ----
    const float* bs = basis + bidx * 9;
    #pragma unroll
    for (int i = 0; i < 2; ++i) {
        const int d  = lane + i * 64;
        const float cx = V[i][0] - v0x, cy = V[i][1] - v0y, cz = V[i][2] - v0z;
        const float xx = X[i][0], xy = X[i][1], xz = X[i][2];
        const float xn = sqrtf(xx*xx + xy*xy + xz*xz) + EPSF;
        const float vn = sqrtf(cx*cx + cy*cy + cz*cz) + EPSF;
        const float ixn = 1.f/xn, ivn = 1.f/vn;
        float f[20];
        #pragma unroll
        for (int k = 0; k < 10; ++k) f[k] = fs[k];
        f[10] = xn;
        f[11] = (xx*bs[0] + xy*bs[1] + xz*bs[2]) * ixn;
        f[12] = (xx*bs[3] + xy*bs[4] + xz*bs[5]) * ixn;
        f[13] = (xx*bs[6] + xy*bs[7] + xz*bs[8]) * ixn;
        f[14] = vn;
        f[15] = (cx*bs[0] + cy*bs[1] + cz*bs[2]) * ivn;
        f[16] = (cx*bs[3] + cy*bs[4] + cz*bs[5]) * ivn;
        f[17] = (cx*bs[6] + cy*bs[7] + cz*bs[8]) * ivn;
        f[18] = (xx*cx + xy*cy + xz*cz) * ixn * ivn;
        f[19] = 1.0f;                         // bias-as-feature
        const int mt  = d >> 4;
        const int r16 = d & 15;
        uint4* base = reinterpret_cast<uint4*>(&featb[((w << 9) + (mt << 6) + r16) * 8]);
        uint4 pk0, pk1, pk2;
        pk0.x = cvt_pk_bf16(f[0],  f[1]);  pk0.y = cvt_pk_bf16(f[2],  f[3]);
        pk0.z = cvt_pk_bf16(f[4],  f[5]);  pk0.w = cvt_pk_bf16(f[6],  f[7]);
        pk1.x = cvt_pk_bf16(f[8],  f[9]);  pk1.y = cvt_pk_bf16(f[10], f[11]);
        pk1.z = cvt_pk_bf16(f[12], f[13]); pk1.w = cvt_pk_bf16(f[14], f[15]);
        pk2.x = cvt_pk_bf16(f[16], f[17]); pk2.y = cvt_pk_bf16(f[18], f[19]);
        pk2.z = 0u; pk2.w = 0u;
        base[0]  = pk0;      // kb=0 rows (k0..7)
        base[16] = pk1;      // kb=1 rows (k8..15), +16*16B
        base[32] = pk2;      // kb=2 rows (k16..19,0,0)
        base[48] = uint4{0u,0u,0u,0u};   // kb=3 rows (zero)
    }
    __syncthreads();   // the only barrier

    // ---- MFMA phase: per wave, loop t; psum live only within one t ----
    const f32x4 zc = {0.f, 0.f, 0.f, 0.f};
    #pragma unroll 1
    for (int t = 0; t < T; ++t) {
        f32x4 psum[4];
        #pragma unroll
        for (int nt = 0; nt < 4; ++nt)
            #pragma unroll
            for (int r = 0; r < 4; ++r) psum[nt][r] = 0.f;

        #pragma unroll
        for (int mt = 0; mt < 8; ++mt) {
            const short8 af = *reinterpret_cast<const short8*>(
                &featb[((t << 9) + (mt << 6) + lane) * 8]);
            #pragma unroll
            for (int nt = 0; nt < 4; ++nt) {
                f32x4 d = __builtin_amdgcn_mfma_f32_16x16x32_bf16(af, bfrag[nt], zc, 0, 0, 0);
                #pragma unroll
                for (int r = 0; r < 4; ++r) {
                    const float a = d[r];
                    // leaky(a) = 0.505a + 0.495|a| : 2 FMAs, abs is a free modifier
                    psum[nt][r] = fmaf(0.505f, a, fmaf(0.495f, fabsf(a), psum[nt][r]));
                }
            }
        }

        // epilogue for this t: column pool across lane groups, write hm
        const int gg = blockIdx.x * T + t;
        #pragma unroll
        for (int nt = 0; nt < 4; ++nt) {
            float s4 = psum[nt][0] + psum[nt][1] + psum[nt][2] + psum[nt][3];
            s4 += __shfl_xor(s4, 16, 64);
            s4 += __shfl_xor(s4, 32, 64);
            if (lane < 16)
                hm_out[(size_t)gg * H + w * 64 + nt * 16 + lane] = s4 * invd;
        }
    }
}

// Kernel B: layers 1-2, 8 t per block (unchanged)
__global__ __launch_bounds__(256) void k_l12(
    const float* __restrict__ hm, const float* __restrict__ W1,
    const float* __restrict__ b1, const float* __restrict__ W2,
    const float* __restrict__ b2, float* __restrict__ out)
{
    const int tb  = blockIdx.x * 8;
    const int tid = threadIdx.x;
    __shared__ float hs[8][H];
    __shared__ float h1[8][H];

    {
        const float4* src = reinterpret_cast<const float4*>(hm + (size_t)tb * H);
        float4* dst = reinterpret_cast<float4*>(&hs[0][0]);
        #pragma unroll
        for (int i = 0; i < 2; ++i) dst[tid + i*256] = src[tid + i*256];
    }
    __syncthreads();

    {
        float acc[8];
        const float bb = b1[tid];
        #pragma unroll
        for (int t = 0; t < 8; ++t) acc[t] = bb;
        for (int k = 0; k < H; ++k) {
            const float w = W1[(size_t)k * H + tid];
            #pragma unroll
            for (int t = 0; t < 8; ++t) acc[t] = fmaf(hs[t][k], w, acc[t]);
        }
        #pragma unroll
        for (int t = 0; t < 8; ++t) {
            float a = acc[t];
            h1[t][tid] = (a > 0.f) ? a : 0.01f * a;
        }
    }
    __syncthreads();

    {
        const int n  = tid & 127;
        const int t0 = (tid >> 7) * 4;
        float acc[4];
        const float bb = b2[n];
        #pragma unroll
        for (int t = 0; t < 4; ++t) acc[t] = bb;
        for (int k = 0; k < H; ++k) {
            const float w = W2[(size_t)k * L + n];
            #pragma unroll
            for (int t = 0; t < 4; ++t) acc[t] = fmaf(h1[t0 + t][k], w, acc[t]);
        }
        #pragma unroll
        for (int t = 0; t < 4; ++t)
            out[(size_t)(tb + t0 + t) * L + n] = acc[t];
    }
}

extern "C" void kernel_launch(void* const* d_in, const int* in_sizes, int n_in,
                              void* d_out, int out_size, void* d_ws, size_t ws_size,
                              hipStream_t stream) {
    const float* x0    = (const float*)d_in[0];
    const float* x     = (const float*)d_in[1];
    const int*   Nv    = (const int*)  d_in[2];
    const float* basis = (const float*)d_in[3];
    const float* v     = (const float*)d_in[4];
    const float* W0    = (const float*)d_in[5];
    const float* b0    = (const float*)d_in[6];
    const float* W1    = (const float*)d_in[7];
    const float* b1    = (const float*)d_in[8];
    const float* W2    = (const float*)d_in[9];
    const float* b2    = (const float*)d_in[10];
    float* out = (float*)d_out;
    float* hm  = (float*)d_ws;          // 4096*256*4 = 4 MB

    hipLaunchKernelGGL(k_feat_l0, dim3(4 * NT / T), dim3(256), 0, stream,
                       x0, x, Nv, basis, v, W0, b0, hm);
    hipLaunchKernelGGL(k_l12, dim3(4 * NT / 8), dim3(256), 0, stream,
                       hm, W1, b1, W2, b2, out);
}